// Round 9
// baseline (282.568 us; speedup 1.0000x reference)
//
#include <hip/hip_runtime.h>

// Problem constants
#define BATCH 4
#define SEQ 2048
#define DM 1024
#define NH 16
#define DK 64

typedef unsigned short u16;
typedef unsigned int u32;
typedef __attribute__((ext_vector_type(8))) short bfrag;    // 8 bf16 (MFMA x32 A/B)
typedef __attribute__((ext_vector_type(4))) float ffrag;    // 4 fp32 (MFMA C/D)

__device__ inline u16 f2bf(float f) {
  union { float f; u32 u; } v; v.f = f;
  u32 u = v.u;
  return (u16)((u + 0x7FFFu + ((u >> 16) & 1u)) >> 16);  // RNE
}
__device__ inline float bf2f(u16 u) {
  union { u32 u; float f; } v; v.u = ((u32)u) << 16;
  return v.f;
}
__device__ inline ffrag MFMA(bfrag a, bfrag b, ffrag c) {
  return __builtin_amdgcn_mfma_f32_16x16x32_bf16(a, b, c, 0, 0, 0);
}

// async global -> LDS, 16 bytes per lane (wave-uniform base + lane*16)
__device__ __forceinline__ void g2l16(const u16* g, u16* l) {
  __builtin_amdgcn_global_load_lds(
      (const __attribute__((address_space(1))) u16*)g,
      (__attribute__((address_space(3))) u16*)l, 16, 0, 0);
}

// ---------------- fused fp32 -> bf16 conversion (x + 4 weights, one launch).
// blocks [0,8192): x (8M floats). blocks [8192,12288): weights, 1024 blocks each.
__global__ __launch_bounds__(256) void cvt_all(
    const float* __restrict__ x,
    const float* __restrict__ a, const float* __restrict__ b,
    const float* __restrict__ c, const float* __restrict__ d,
    u16* __restrict__ ox,
    u16* __restrict__ oa, u16* __restrict__ ob,
    u16* __restrict__ oc, u16* __restrict__ od) {
  int blk = blockIdx.x;
  const float* in;
  u16* out;
  int i;
  if (blk < 8192) {
    in = x; out = ox; i = blk * 256 + threadIdx.x;
  } else {
    int wb = blk - 8192;
    int which = wb >> 10;
    in = which == 0 ? a : which == 1 ? b : which == 2 ? c : d;
    out = which == 0 ? oa : which == 1 ? ob : which == 2 ? oc : od;
    i = (wb & 1023) * 256 + threadIdx.x;
  }
  float4 v = ((const float4*)in)[i];
  union { u16 u[4]; uint2 dd; } o;
  o.u[0] = f2bf(v.x); o.u[1] = f2bf(v.y); o.u[2] = f2bf(v.z); o.u[3] = f2bf(v.w);
  ((uint2*)out)[i] = o.dd;
}

// ---------------- fused Q/K/V projection (R9: double-buffered staging).
// Old loop was {barrier; DMA(cur); barrier; compute(cur)} — zero intra-block
// DMA/compute overlap. New: BK=32, LDS [2][128*32] per matrix (32KB total,
// occupancy unchanged), ONE barrier per K-tile, stage(t+1) issued before
// compute(t) — attn's proven pattern. LDS 4-slot XOR swizzle
// (slot ^= (row>>1)&3, on pre-swizzled global source per rule #21; read slot
// sq loop-invariant) -> 2-way banks (free) vs 8-way row-aligned.
// Operand roles + vectorized epilogues from R8 (harness-verified):
//   z=0 (Q), z=1 (K): A=W (out-dim = m), B=x; z=2 (V): A=x, B=W.
// XCD-ownership remap as R6.
__global__ __launch_bounds__(256) void gemm_qkv(
    const u16* __restrict__ xb,
    const u16* __restrict__ Wq, const u16* __restrict__ Wk,
    const u16* __restrict__ Wv,
    u16* __restrict__ Qb, u16* __restrict__ Ksw, u16* __restrict__ Vsw) {
  const int bid = blockIdx.x;
  const int xcd = bid & 7, s8 = bid >> 3;     // 192 blocks per XCD
  const int ym = (xcd << 3) | (s8 & 7);       // token-panel in [8*xcd, 8*xcd+8)
  const int xn = (s8 >> 3) & 7;
  const int z = s8 >> 6;
  const u16* Bm = z == 0 ? Wq : z == 1 ? Wk : Wv;

  const int K = DM;
  const int bm = ym * 128, bn = xn * 128;
  __shared__ __align__(16) u16 As[2][128 * 32];
  __shared__ __align__(16) u16 Bs[2][128 * 32];
  const int tid = threadIdx.x;
  const int lane = tid & 63;
  const int w = tid >> 6;
  const int wr = w >> 1, wc = w & 1;
  const int l15 = lane & 15, quad = lane >> 4;
  // staging: call c covers rows [c*64, c*64+64); thread row c*64+(tid>>2),
  // LDS 16B-slot tid&3; global source slot = (tid&3) ^ ((row>>1)&3)
  // ((tid>>3)&3 — same for both calls since c*64 keeps (row>>1)&3 invariant)
  const int srow = tid >> 2;
  const int scol = (((tid & 3) ^ ((tid >> 3) & 3)) * 8);
  // fragment-read slot (loop-invariant): quad ^ ((l15>>1)&3)
  const int sq = (quad ^ ((l15 >> 1) & 3)) * 8;

  ffrag acc[4][4] = {};

  // prologue: stage K-tile 0 into buf 0
  g2l16(&xb[(size_t)(bm + srow) * K + scol], &As[0][tid * 8]);
  g2l16(&xb[(size_t)(bm + 64 + srow) * K + scol], &As[0][(tid + 256) * 8]);
  g2l16(&Bm[(size_t)(bn + srow) * K + scol], &Bs[0][tid * 8]);
  g2l16(&Bm[(size_t)(bn + 64 + srow) * K + scol], &Bs[0][(tid + 256) * 8]);

  for (int kt = 0; kt < K / 32; ++kt) {
    const int buf = kt & 1;
    __syncthreads();   // stage(kt) complete; all waves' reads of buf^1 done
    if (kt + 1 < K / 32) {
      const int k1 = (kt + 1) * 32;
      g2l16(&xb[(size_t)(bm + srow) * K + k1 + scol], &As[buf ^ 1][tid * 8]);
      g2l16(&xb[(size_t)(bm + 64 + srow) * K + k1 + scol], &As[buf ^ 1][(tid + 256) * 8]);
      g2l16(&Bm[(size_t)(bn + srow) * K + k1 + scol], &Bs[buf ^ 1][tid * 8]);
      g2l16(&Bm[(size_t)(bn + 64 + srow) * K + k1 + scol], &Bs[buf ^ 1][(tid + 256) * 8]);
    }
    bfrag af[4], bf[4];
    if (z == 2) {   // V: A = x (tokens as m), B = W (out-dims as n)
#pragma unroll
      for (int i = 0; i < 4; i++)
        af[i] = *(const bfrag*)(&As[buf][(wr * 64 + i * 16 + l15) * 32 + sq]);
#pragma unroll
      for (int j = 0; j < 4; j++)
        bf[j] = *(const bfrag*)(&Bs[buf][(wc * 64 + j * 16 + l15) * 32 + sq]);
    } else {        // Q,K: A = W (out-dims as m), B = x (tokens as n)
#pragma unroll
      for (int i = 0; i < 4; i++)
        af[i] = *(const bfrag*)(&Bs[buf][(wr * 64 + i * 16 + l15) * 32 + sq]);
#pragma unroll
      for (int j = 0; j < 4; j++)
        bf[j] = *(const bfrag*)(&As[buf][(wc * 64 + j * 16 + l15) * 32 + sq]);
    }
#pragma unroll
    for (int i = 0; i < 4; i++)
#pragma unroll
      for (int j = 0; j < 4; j++)
        acc[i][j] = MFMA(af[i], bf[j], acc[i][j]);
  }

  if (z == 0) {
    // m = out-dim (bn side), n = token (bm side); r on d -> uint2
#pragma unroll
    for (int i = 0; i < 4; i++)
#pragma unroll
      for (int j = 0; j < 4; j++) {
        int mo = bn + wr * 64 + i * 16 + quad * 4;
        int nt = bm + wc * 64 + j * 16 + l15;
        int b = nt >> 11, s = nt & 2047;
        int h = mo >> 6, d = mo & 63;
        union { u16 u[4]; uint2 dd; } o;
#pragma unroll
        for (int r = 0; r < 4; r++) o.u[r] = f2bf(acc[i][j][r]);
        *(uint2*)(&Qb[(((size_t)(b * NH + h)) * SEQ + s) * DK + d]) = o.dd;
      }
  } else if (z == 1) {
    // m = out-dim d (bn side), n = token (bm side); e = (quad&1)*4 + r
#pragma unroll
    for (int i = 0; i < 4; i++)
#pragma unroll
      for (int j = 0; j < 4; j++) {
        int nt = bm + wc * 64 + j * 16 + l15;
        int mo = bn + wr * 64 + i * 16 + quad * 4;
        int b = nt >> 11, s = nt & 2047;
        int h = mo >> 6;
        size_t hb = (size_t)(b * NH + h) * (SEQ * DK);
        size_t off = hb + (size_t)(s >> 6) * 4096 +
            (size_t)((j * 2 + (i >> 1)) * 64 +
                     ((i * 2 + (quad >> 1)) & 3) * 16 + l15) * 8 +
            (quad & 1) * 4;
        union { u16 u[4]; uint2 dd; } o;
#pragma unroll
        for (int r = 0; r < 4; r++) o.u[r] = f2bf(acc[i][j][r]);
        *(uint2*)(&Ksw[off]) = o.dd;
      }
  } else {
    // m = token (bm side), n = out-dim (bn side); e = (i&1)*4 + r
#pragma unroll
    for (int i = 0; i < 4; i++)
#pragma unroll
      for (int j = 0; j < 4; j++) {
        int mt = bm + wr * 64 + i * 16 + quad * 4;
        int no = bn + wc * 64 + j * 16 + l15;
        int b = mt >> 11, s = mt & 2047;
        int h = no >> 6;
        size_t hb = (size_t)(b * NH + h) * (SEQ * DK);
        size_t off = hb + (size_t)(s >> 6) * 4096 +
            (size_t)((j * 2 + (i >> 1)) * 64 + quad * 16 + l15) * 8 +
            (i & 1) * 4;
        union { u16 u[4]; uint2 dd; } o;
#pragma unroll
        for (int r = 0; r < 4; r++) o.u[r] = f2bf(acc[i][j][r]);
        *(uint2*)(&Vsw[off]) = o.dd;
      }
  }
}

// ---------------- out projection GEMM (R9: same double-buffered staging;
// swapped operands so out-dim is the r-axis -> C float4; XCD remap as R6).
__global__ __launch_bounds__(256) void gemm_out(
    const u16* __restrict__ Ab, const u16* __restrict__ Wo, float* __restrict__ C) {
  const int K = DM, N = DM;
  const int bid = blockIdx.x;
  const int xcd = bid & 7, s8 = bid >> 3;     // 64 blocks per XCD
  const int ym = (xcd << 3) | (s8 & 7);
  const int xn = s8 >> 3;
  const int bm = ym * 128, bn = xn * 128;
  __shared__ __align__(16) u16 As[2][128 * 32];
  __shared__ __align__(16) u16 Bs[2][128 * 32];
  const int tid = threadIdx.x;
  const int lane = tid & 63;
  const int w = tid >> 6;
  const int wr = w >> 1, wc = w & 1;
  const int l15 = lane & 15, quad = lane >> 4;
  const int srow = tid >> 2;
  const int scol = (((tid & 3) ^ ((tid >> 3) & 3)) * 8);
  const int sq = (quad ^ ((l15 >> 1) & 3)) * 8;

  ffrag acc[4][4] = {};

  g2l16(&Ab[(size_t)(bm + srow) * K + scol], &As[0][tid * 8]);
  g2l16(&Ab[(size_t)(bm + 64 + srow) * K + scol], &As[0][(tid + 256) * 8]);
  g2l16(&Wo[(size_t)(bn + srow) * K + scol], &Bs[0][tid * 8]);
  g2l16(&Wo[(size_t)(bn + 64 + srow) * K + scol], &Bs[0][(tid + 256) * 8]);

  for (int kt = 0; kt < K / 32; ++kt) {
    const int buf = kt & 1;
    __syncthreads();
    if (kt + 1 < K / 32) {
      const int k1 = (kt + 1) * 32;
      g2l16(&Ab[(size_t)(bm + srow) * K + k1 + scol], &As[buf ^ 1][tid * 8]);
      g2l16(&Ab[(size_t)(bm + 64 + srow) * K + k1 + scol], &As[buf ^ 1][(tid + 256) * 8]);
      g2l16(&Wo[(size_t)(bn + srow) * K + k1 + scol], &Bs[buf ^ 1][tid * 8]);
      g2l16(&Wo[(size_t)(bn + 64 + srow) * K + k1 + scol], &Bs[buf ^ 1][(tid + 256) * 8]);
    }
    bfrag af[4], bf[4];
#pragma unroll
    for (int i = 0; i < 4; i++)
      af[i] = *(const bfrag*)(&Bs[buf][(wr * 64 + i * 16 + l15) * 32 + sq]);
#pragma unroll
    for (int j = 0; j < 4; j++)
      bf[j] = *(const bfrag*)(&As[buf][(wc * 64 + j * 16 + l15) * 32 + sq]);
#pragma unroll
    for (int i = 0; i < 4; i++)
#pragma unroll
      for (int j = 0; j < 4; j++)
        acc[i][j] = MFMA(af[i], bf[j], acc[i][j]);
  }

  // m = out-dim (bn side), n = token (bm side): C[token][outdim] float4
#pragma unroll
  for (int i = 0; i < 4; i++)
#pragma unroll
    for (int j = 0; j < 4; j++) {
      int no = bn + wr * 64 + i * 16 + quad * 4;
      int mt = bm + wc * 64 + j * 16 + l15;
      *(ffrag*)(&C[(size_t)mt * N + no]) = acc[i][j];
    }
}

// ---------------- Flash attention (R8 body, byte-identical: full-rate x32 PV,
// VALU lsum + shuffle reduce, XCD transpose (bx=head), g2l16 double-buffered
// K/V staging, T5 setprio).
__global__ __launch_bounds__(256) void attn(
    const u16* __restrict__ Qb, const u16* __restrict__ Ksw,
    const u16* __restrict__ Vsw, u16* __restrict__ Ab) {
  const int bh = blockIdx.x;
  const int b = bh >> 4, h = bh & 15;
  const int qbase = blockIdx.y * 128;
  const int tid = threadIdx.x;
  const int w = tid >> 6, lane = tid & 63;
  const int l15 = lane & 15, quad = lane >> 4;

  __shared__ __align__(16) u16 Kt[2][4096];   // swizzled 64x64 K tile, dbuf
  __shared__ __align__(16) u16 Vt[2][4096];   // swizzled 64x64 V tile, dbuf

  const size_t hbase = (size_t)bh * SEQ * DK;

  // Q fragments (B-operand: n=q=l15, k=d=quad*8+e) scaled by 0.125*log2e
  const float qscale = 0.125f * 1.4426950408889634f;
  bfrag q[2][2];
#pragma unroll
  for (int i = 0; i < 2; i++)
#pragma unroll
    for (int kk = 0; kk < 2; kk++) {
      bfrag t = *(const bfrag*)(&Qb[hbase +
          (size_t)(qbase + w * 32 + i * 16 + l15) * DK + kk * 32 + quad * 8]);
#pragma unroll
      for (int e = 0; e < 8; e++)
        q[i][kk][e] = (short)f2bf(bf2f((u16)t[e]) * qscale);
    }

  ffrag O[4][2] = {};      // O^T accs: [d-block][q-block]
  float lsum[2] = {0.f, 0.f};

  // prefetch tile 0 (K: 8KB = 2 DMA calls; V: 8KB = 2 DMA calls)
  {
    const u16* ks = &Ksw[hbase];
    const u16* vs = &Vsw[hbase];
    g2l16(&ks[tid * 8], &Kt[0][tid * 8]);
    g2l16(&ks[2048 + tid * 8], &Kt[0][2048 + tid * 8]);
    g2l16(&vs[tid * 8], &Vt[0][tid * 8]);
    g2l16(&vs[2048 + tid * 8], &Vt[0][2048 + tid * 8]);
  }

  for (int t = 0; t < SEQ / 64; t++) {
    const int buf = t & 1;
    __syncthreads();   // DMA for tile t complete; prior reads of buf^1 done
    if (t + 1 < SEQ / 64) {
      const u16* ks = &Ksw[hbase + (size_t)(t + 1) * 4096];
      const u16* vs = &Vsw[hbase + (size_t)(t + 1) * 4096];
      g2l16(&ks[tid * 8], &Kt[buf ^ 1][tid * 8]);
      g2l16(&ks[2048 + tid * 8], &Kt[buf ^ 1][2048 + tid * 8]);
      g2l16(&vs[tid * 8], &Vt[buf ^ 1][tid * 8]);
      g2l16(&vs[2048 + tid * 8], &Vt[buf ^ 1][2048 + tid * 8]);
    }

    __builtin_amdgcn_s_setprio(1);
    u32 pb[4][2][2];                  // P bf16x4 per (kv16-block j, q-block i)
#pragma unroll
    for (int j = 0; j < 4; j++) {     // kv 16-block
      bfrag k0f = *(const bfrag*)(&Kt[buf][((j * 2 + 0) * 64 + lane) * 8]);
      bfrag k1f = *(const bfrag*)(&Kt[buf][((j * 2 + 1) * 64 + lane) * 8]);
#pragma unroll
      for (int i = 0; i < 2; i++) {   // q 16-block
        ffrag z = {};
        z = MFMA(k0f, q[i][0], z);
        z = MFMA(k1f, q[i][1], z);    // S^T block: lane (q=l15, s=quad*4+r)
        u32 u[4]; float ts = 0.f;
#pragma unroll
        for (int r = 0; r < 4; r++) {
          float p = __builtin_amdgcn_exp2f(z[r]);
          u[r] = __float_as_uint(p);
          ts += __uint_as_float(u[r] & 0xffff0000u);
        }
        lsum[i] += ts;
        pb[j][i][0] = __builtin_amdgcn_perm(u[1], u[0], 0x07060302u);
        pb[j][i][1] = __builtin_amdgcn_perm(u[3], u[2], 0x07060302u);
      }
    }

    // O^T += V^T . P^T, x32 MFMA: window wnd covers kv16-blocks {2wnd,2wnd+1};
    // B-operand = register concat of the two P fragments (k-slot map matches
    // the Vsw swizzle by construction). V A-frags lane-linear b128.
#pragma unroll
    for (int wnd = 0; wnd < 2; wnd++) {
      union { u32 d[4]; bfrag v; } px0, px1;
      px0.d[0] = pb[2 * wnd][0][0];     px0.d[1] = pb[2 * wnd][0][1];
      px0.d[2] = pb[2 * wnd + 1][0][0]; px0.d[3] = pb[2 * wnd + 1][0][1];
      px1.d[0] = pb[2 * wnd][1][0];     px1.d[1] = pb[2 * wnd][1][1];
      px1.d[2] = pb[2 * wnd + 1][1][0]; px1.d[3] = pb[2 * wnd + 1][1][1];
#pragma unroll
      for (int db = 0; db < 4; db++) {
        bfrag vf = *(const bfrag*)(&Vt[buf][((db * 2 + wnd) * 64 + lane) * 8]);
        O[db][0] = MFMA(vf, px0.v, O[db][0]);
        O[db][1] = MFMA(vf, px1.v, O[db][1]);
      }
    }
    __builtin_amdgcn_s_setprio(0);
  }

  // reduce lsum across the 4 quads (same q=l15)
  float rl[2];
#pragma unroll
  for (int i = 0; i < 2; i++) {
    float s = lsum[i];
    s += __shfl_xor(s, 16);
    s += __shfl_xor(s, 32);
    rl[i] = 1.0f / s;
  }

  // O^T C-layout: lane holds q=l15, d=quad*4+r. Pack 4 d (8B) per store.
  const size_t obase = ((size_t)b * SEQ) * DM + (size_t)h * DK;
#pragma unroll
  for (int db = 0; db < 4; db++)
#pragma unroll
    for (int i = 0; i < 2; i++) {
      int s = qbase + w * 32 + i * 16 + l15;
      union { u16 u[4]; uint2 d; } o;
#pragma unroll
      for (int r = 0; r < 4; r++) o.u[r] = f2bf(O[db][i][r] * rl[i]);
      *(uint2*)(&Ab[obase + (size_t)s * DM + db * 16 + quad * 4]) = o.d;
    }
}

extern "C" void kernel_launch(void* const* d_in, const int* in_sizes, int n_in,
                              void* d_out, int out_size, void* d_ws, size_t ws_size,
                              hipStream_t stream) {
  const float* x  = (const float*)d_in[0];
  const float* Wq = (const float*)d_in[1];
  const float* Wk = (const float*)d_in[2];
  const float* Wv = (const float*)d_in[3];
  const float* Wo = (const float*)d_in[4];
  float* out = (float*)d_out;

  char* ws = (char*)d_ws;
  u16* xb  = (u16*)(ws + 0);          // 16 MB
  u16* Wqb = (u16*)(ws + 16777216);
  u16* Wkb = (u16*)(ws + 18874368);
  u16* Wvb = (u16*)(ws + 20971520);
  u16* Wob = (u16*)(ws + 23068672);
  u16* Qb  = (u16*)(ws + 25165824);   // [B,H,S,DK]
  u16* Ksw = (u16*)(ws + 41943040);   // [B,H] x 32 tiles x swizzled 64x64
  u16* Vsw = (u16*)(ws + 58720256);   // [B,H] x 32 tiles x swizzled 64x64 (x32-PV)
  u16* Ab  = (u16*)(ws + 75497472);   // [B,S,DM]
  const size_t NEED = 92274688;
  if (ws_size < NEED) return;

  cvt_all<<<12288, 256, 0, stream>>>(x, Wq, Wk, Wv, Wo, xb, Wqb, Wkb, Wvb, Wob);

  gemm_qkv<<<1536, 256, 0, stream>>>(xb, Wqb, Wkb, Wvb, Qb, Ksw, Vsw);

  dim3 gat(BATCH * NH, SEQ / 128);
  attn<<<gat, 256, 0, stream>>>(Qb, Ksw, Vsw, Ab);

  gemm_out<<<512, 256, 0, stream>>>(Ab, Wob, out);
}

// Round 10
// 252.053 us; speedup vs baseline: 1.1211x; 1.1211x over previous
//
#include <hip/hip_runtime.h>

// Problem constants
#define BATCH 4
#define SEQ 2048
#define DM 1024
#define NH 16
#define DK 64

typedef unsigned short u16;
typedef unsigned int u32;
typedef __attribute__((ext_vector_type(8))) short bfrag;    // 8 bf16 (MFMA x32 A/B)
typedef __attribute__((ext_vector_type(4))) float ffrag;    // 4 fp32 (MFMA C/D)

__device__ inline u16 f2bf(float f) {
  union { float f; u32 u; } v; v.f = f;
  u32 u = v.u;
  return (u16)((u + 0x7FFFu + ((u >> 16) & 1u)) >> 16);  // RNE
}
__device__ inline float bf2f(u16 u) {
  union { u32 u; float f; } v; v.u = ((u32)u) << 16;
  return v.f;
}
__device__ inline ffrag MFMA(bfrag a, bfrag b, ffrag c) {
  return __builtin_amdgcn_mfma_f32_16x16x32_bf16(a, b, c, 0, 0, 0);
}

// async global -> LDS, 16 bytes per lane (wave-uniform base + lane*16)
__device__ __forceinline__ void g2l16(const u16* g, u16* l) {
  __builtin_amdgcn_global_load_lds(
      (const __attribute__((address_space(1))) u16*)g,
      (__attribute__((address_space(3))) u16*)l, 16, 0, 0);
}

// ---------------- fused fp32 -> bf16 conversion (x + 4 weights, one launch).
// blocks [0,8192): x (8M floats). blocks [8192,12288): weights, 1024 blocks each.
__global__ __launch_bounds__(256) void cvt_all(
    const float* __restrict__ x,
    const float* __restrict__ a, const float* __restrict__ b,
    const float* __restrict__ c, const float* __restrict__ d,
    u16* __restrict__ ox,
    u16* __restrict__ oa, u16* __restrict__ ob,
    u16* __restrict__ oc, u16* __restrict__ od) {
  int blk = blockIdx.x;
  const float* in;
  u16* out;
  int i;
  if (blk < 8192) {
    in = x; out = ox; i = blk * 256 + threadIdx.x;
  } else {
    int wb = blk - 8192;
    int which = wb >> 10;
    in = which == 0 ? a : which == 1 ? b : which == 2 ? c : d;
    out = which == 0 ? oa : which == 1 ? ob : which == 2 ? oc : od;
    i = (wb & 1023) * 256 + threadIdx.x;
  }
  float4 v = ((const float4*)in)[i];
  union { u16 u[4]; uint2 dd; } o;
  o.u[0] = f2bf(v.x); o.u[1] = f2bf(v.y); o.u[2] = f2bf(v.z); o.u[3] = f2bf(v.w);
  ((uint2*)out)[i] = o.dd;
}

// ---------------- fused Q/K/V projection (R10 = R8 structure, R9's explicit
// dbuf reverted — it reproduced the documented m99/m100 null and cost 14µs.
// Single-buffer BK=64, XOR-swizzled LDS (rule #21: pre-swizzled global source,
// same involution on fragment reads), XCD-ownership remap, per-output operand
// roles + vectorized uint2 epilogues (all harness-verified in R8).
//   z=0 (Q), z=1 (K): A=W (out-dim = m), B=x; z=2 (V): A=x, B=W.
__global__ __launch_bounds__(256) void gemm_qkv(
    const u16* __restrict__ xb,
    const u16* __restrict__ Wq, const u16* __restrict__ Wk,
    const u16* __restrict__ Wv,
    u16* __restrict__ Qb, u16* __restrict__ Ksw, u16* __restrict__ Vsw) {
  const int bid = blockIdx.x;
  const int xcd = bid & 7, s8 = bid >> 3;     // 192 blocks per XCD
  const int ym = (xcd << 3) | (s8 & 7);       // token-panel in [8*xcd, 8*xcd+8)
  const int xn = (s8 >> 3) & 7;
  const int z = s8 >> 6;
  const u16* Bm = z == 0 ? Wq : z == 1 ? Wk : Wv;

  const int K = DM;
  const int bm = ym * 128, bn = xn * 128;
  __shared__ __align__(16) u16 As[128 * 64];
  __shared__ __align__(16) u16 Bs[128 * 64];
  const int tid = threadIdx.x;
  const int lane = tid & 63;
  const int w = tid >> 6;
  const int wr = w >> 1, wc = w & 1;
  const int l15 = lane & 15, quad = lane >> 4;
  const int srow = tid >> 3;
  const int scol = (((tid & 7) ^ (srow & 7)) * 8);

  ffrag acc[4][4] = {};

  for (int k0 = 0; k0 < K; k0 += 64) {
    __syncthreads();
#pragma unroll
    for (int c = 0; c < 4; c++) {
      g2l16(&xb[(size_t)(bm + c * 32 + srow) * K + k0 + scol], &As[c * 2048 + tid * 8]);
      g2l16(&Bm[(size_t)(bn + c * 32 + srow) * K + k0 + scol], &Bs[c * 2048 + tid * 8]);
    }
    __syncthreads();
#pragma unroll
    for (int kk = 0; kk < 2; kk++) {
      bfrag af[4], bf[4];
      if (z == 2) {   // V: A = x (tokens as m), B = W (out-dims as n)
#pragma unroll
        for (int i = 0; i < 4; i++)
          af[i] = *(const bfrag*)(&As[(wr * 64 + i * 16 + l15) * 64 +
                                      ((kk * 4 + quad) ^ (l15 & 7)) * 8]);
#pragma unroll
        for (int j = 0; j < 4; j++)
          bf[j] = *(const bfrag*)(&Bs[(wc * 64 + j * 16 + l15) * 64 +
                                      ((kk * 4 + quad) ^ (l15 & 7)) * 8]);
      } else {        // Q,K: A = W (out-dims as m), B = x (tokens as n)
#pragma unroll
        for (int i = 0; i < 4; i++)
          af[i] = *(const bfrag*)(&Bs[(wr * 64 + i * 16 + l15) * 64 +
                                      ((kk * 4 + quad) ^ (l15 & 7)) * 8]);
#pragma unroll
        for (int j = 0; j < 4; j++)
          bf[j] = *(const bfrag*)(&As[(wc * 64 + j * 16 + l15) * 64 +
                                      ((kk * 4 + quad) ^ (l15 & 7)) * 8]);
      }
#pragma unroll
      for (int i = 0; i < 4; i++)
#pragma unroll
        for (int j = 0; j < 4; j++)
          acc[i][j] = MFMA(af[i], bf[j], acc[i][j]);
    }
  }

  if (z == 0) {
    // m = out-dim (bn side), n = token (bm side); r on d -> uint2
#pragma unroll
    for (int i = 0; i < 4; i++)
#pragma unroll
      for (int j = 0; j < 4; j++) {
        int mo = bn + wr * 64 + i * 16 + quad * 4;
        int nt = bm + wc * 64 + j * 16 + l15;
        int b = nt >> 11, s = nt & 2047;
        int h = mo >> 6, d = mo & 63;
        union { u16 u[4]; uint2 dd; } o;
#pragma unroll
        for (int r = 0; r < 4; r++) o.u[r] = f2bf(acc[i][j][r]);
        *(uint2*)(&Qb[(((size_t)(b * NH + h)) * SEQ + s) * DK + d]) = o.dd;
      }
  } else if (z == 1) {
    // m = out-dim d (bn side), n = token (bm side); e = (quad&1)*4 + r
#pragma unroll
    for (int i = 0; i < 4; i++)
#pragma unroll
      for (int j = 0; j < 4; j++) {
        int nt = bm + wc * 64 + j * 16 + l15;
        int mo = bn + wr * 64 + i * 16 + quad * 4;
        int b = nt >> 11, s = nt & 2047;
        int h = mo >> 6;
        size_t hb = (size_t)(b * NH + h) * (SEQ * DK);
        size_t off = hb + (size_t)(s >> 6) * 4096 +
            (size_t)((j * 2 + (i >> 1)) * 64 +
                     ((i * 2 + (quad >> 1)) & 3) * 16 + l15) * 8 +
            (quad & 1) * 4;
        union { u16 u[4]; uint2 dd; } o;
#pragma unroll
        for (int r = 0; r < 4; r++) o.u[r] = f2bf(acc[i][j][r]);
        *(uint2*)(&Ksw[off]) = o.dd;
      }
  } else {
    // m = token (bm side), n = out-dim (bn side); e = (i&1)*4 + r
#pragma unroll
    for (int i = 0; i < 4; i++)
#pragma unroll
      for (int j = 0; j < 4; j++) {
        int mt = bm + wr * 64 + i * 16 + quad * 4;
        int no = bn + wc * 64 + j * 16 + l15;
        int b = mt >> 11, s = mt & 2047;
        int h = no >> 6;
        size_t hb = (size_t)(b * NH + h) * (SEQ * DK);
        size_t off = hb + (size_t)(s >> 6) * 4096 +
            (size_t)((j * 2 + (i >> 1)) * 64 + quad * 16 + l15) * 8 +
            (i & 1) * 4;
        union { u16 u[4]; uint2 dd; } o;
#pragma unroll
        for (int r = 0; r < 4; r++) o.u[r] = f2bf(acc[i][j][r]);
        *(uint2*)(&Vsw[off]) = o.dd;
      }
  }
}

// ---------------- out projection GEMM (R10 = R8: single-buffer BK=64,
// swapped operands so out-dim is the r-axis -> C float4; XCD remap).
__global__ __launch_bounds__(256) void gemm_out(
    const u16* __restrict__ Ab, const u16* __restrict__ Wo, float* __restrict__ C) {
  const int K = DM, N = DM;
  const int bid = blockIdx.x;
  const int xcd = bid & 7, s8 = bid >> 3;     // 64 blocks per XCD
  const int ym = (xcd << 3) | (s8 & 7);
  const int xn = s8 >> 3;
  const int bm = ym * 128, bn = xn * 128;
  __shared__ __align__(16) u16 As[128 * 64];
  __shared__ __align__(16) u16 Bs[128 * 64];
  const int tid = threadIdx.x;
  const int lane = tid & 63;
  const int w = tid >> 6;
  const int wr = w >> 1, wc = w & 1;
  const int l15 = lane & 15, quad = lane >> 4;
  const int srow = tid >> 3;
  const int scol = (((tid & 7) ^ (srow & 7)) * 8);

  ffrag acc[4][4] = {};

  for (int k0 = 0; k0 < K; k0 += 64) {
    __syncthreads();
#pragma unroll
    for (int c = 0; c < 4; c++) {
      g2l16(&Ab[(size_t)(bm + c * 32 + srow) * K + k0 + scol], &As[c * 2048 + tid * 8]);
      g2l16(&Wo[(size_t)(bn + c * 32 + srow) * K + k0 + scol], &Bs[c * 2048 + tid * 8]);
    }
    __syncthreads();
#pragma unroll
    for (int kk = 0; kk < 2; kk++) {
      bfrag af[4], bf[4];
#pragma unroll
      for (int i = 0; i < 4; i++)
        af[i] = *(const bfrag*)(&Bs[(wr * 64 + i * 16 + l15) * 64 +
                                    ((kk * 4 + quad) ^ (l15 & 7)) * 8]);
#pragma unroll
      for (int j = 0; j < 4; j++)
        bf[j] = *(const bfrag*)(&As[(wc * 64 + j * 16 + l15) * 64 +
                                    ((kk * 4 + quad) ^ (l15 & 7)) * 8]);
#pragma unroll
      for (int i = 0; i < 4; i++)
#pragma unroll
        for (int j = 0; j < 4; j++)
          acc[i][j] = MFMA(af[i], bf[j], acc[i][j]);
    }
  }

  // m = out-dim (bn side), n = token (bm side): C[token][outdim] float4
#pragma unroll
  for (int i = 0; i < 4; i++)
#pragma unroll
    for (int j = 0; j < 4; j++) {
      int no = bn + wr * 64 + i * 16 + quad * 4;
      int mt = bm + wc * 64 + j * 16 + l15;
      *(ffrag*)(&C[(size_t)mt * N + no]) = acc[i][j];
    }
}

// ---------------- Flash attention (R10: x32-PV body + ones-matrix lsum on
// the MFMA pipe). lsum = ones.P^T via 4 extra full-rate x32 MFMAs/tile on the
// SAME px operands PV consumes (R4's x16 version failed on serialization +
// VGPR; both causes gone here). A=ones is layout-independent, so every lane's
// C value is the window column-sum for its q=l15 — sums the exact truncated
// bf16 P (perm truncates like the old AND mask), and the final shuffle
// reduce disappears. VALU per fragment: 4 exp2 + 2 perm only.
// Rest: XCD transpose (bx=head), g2l16 double-buffered K/V staging, setprio.
__global__ __launch_bounds__(256) void attn(
    const u16* __restrict__ Qb, const u16* __restrict__ Ksw,
    const u16* __restrict__ Vsw, u16* __restrict__ Ab) {
  const int bh = blockIdx.x;
  const int b = bh >> 4, h = bh & 15;
  const int qbase = blockIdx.y * 128;
  const int tid = threadIdx.x;
  const int w = tid >> 6, lane = tid & 63;
  const int l15 = lane & 15, quad = lane >> 4;

  __shared__ __align__(16) u16 Kt[2][4096];   // swizzled 64x64 K tile, dbuf
  __shared__ __align__(16) u16 Vt[2][4096];   // swizzled 64x64 V tile, dbuf

  const size_t hbase = (size_t)bh * SEQ * DK;

  // Q fragments (B-operand: n=q=l15, k=d=quad*8+e) scaled by 0.125*log2e
  const float qscale = 0.125f * 1.4426950408889634f;
  bfrag q[2][2];
#pragma unroll
  for (int i = 0; i < 2; i++)
#pragma unroll
    for (int kk = 0; kk < 2; kk++) {
      bfrag t = *(const bfrag*)(&Qb[hbase +
          (size_t)(qbase + w * 32 + i * 16 + l15) * DK + kk * 32 + quad * 8]);
#pragma unroll
      for (int e = 0; e < 8; e++)
        q[i][kk][e] = (short)f2bf(bf2f((u16)t[e]) * qscale);
    }

  const bfrag vones = {(short)0x3F80, (short)0x3F80, (short)0x3F80, (short)0x3F80,
                       (short)0x3F80, (short)0x3F80, (short)0x3F80, (short)0x3F80};

  ffrag O[4][2] = {};      // O^T accs: [d-block][q-block]
  ffrag Ls[2] = {};        // lsum accs (ones.P^T; every lane holds full sum)

  // prefetch tile 0 (K: 8KB = 2 DMA calls; V: 8KB = 2 DMA calls)
  {
    const u16* ks = &Ksw[hbase];
    const u16* vs = &Vsw[hbase];
    g2l16(&ks[tid * 8], &Kt[0][tid * 8]);
    g2l16(&ks[2048 + tid * 8], &Kt[0][2048 + tid * 8]);
    g2l16(&vs[tid * 8], &Vt[0][tid * 8]);
    g2l16(&vs[2048 + tid * 8], &Vt[0][2048 + tid * 8]);
  }

  for (int t = 0; t < SEQ / 64; t++) {
    const int buf = t & 1;
    __syncthreads();   // DMA for tile t complete; prior reads of buf^1 done
    if (t + 1 < SEQ / 64) {
      const u16* ks = &Ksw[hbase + (size_t)(t + 1) * 4096];
      const u16* vs = &Vsw[hbase + (size_t)(t + 1) * 4096];
      g2l16(&ks[tid * 8], &Kt[buf ^ 1][tid * 8]);
      g2l16(&ks[2048 + tid * 8], &Kt[buf ^ 1][2048 + tid * 8]);
      g2l16(&vs[tid * 8], &Vt[buf ^ 1][tid * 8]);
      g2l16(&vs[2048 + tid * 8], &Vt[buf ^ 1][2048 + tid * 8]);
    }

    __builtin_amdgcn_s_setprio(1);
    u32 pb[4][2][2];                  // P bf16x4 per (kv16-block j, q-block i)
#pragma unroll
    for (int j = 0; j < 4; j++) {     // kv 16-block
      bfrag k0f = *(const bfrag*)(&Kt[buf][((j * 2 + 0) * 64 + lane) * 8]);
      bfrag k1f = *(const bfrag*)(&Kt[buf][((j * 2 + 1) * 64 + lane) * 8]);
#pragma unroll
      for (int i = 0; i < 2; i++) {   // q 16-block
        ffrag z = {};
        z = MFMA(k0f, q[i][0], z);
        z = MFMA(k1f, q[i][1], z);    // S^T block: lane (q=l15, s=quad*4+r)
        u32 u[4];
#pragma unroll
        for (int r = 0; r < 4; r++)
          u[r] = __float_as_uint(__builtin_amdgcn_exp2f(z[r]));
        pb[j][i][0] = __builtin_amdgcn_perm(u[1], u[0], 0x07060302u);
        pb[j][i][1] = __builtin_amdgcn_perm(u[3], u[2], 0x07060302u);
      }
    }

    // O^T += V^T . P^T, x32 MFMA: window wnd covers kv16-blocks {2wnd,2wnd+1};
    // B-operand = register concat of the two P fragments (k-slot map matches
    // the Vsw swizzle by construction). V A-frags lane-linear b128.
    // Ls += ones . P^T on the same px operands (lsum on the matrix pipe).
#pragma unroll
    for (int wnd = 0; wnd < 2; wnd++) {
      union { u32 d[4]; bfrag v; } px0, px1;
      px0.d[0] = pb[2 * wnd][0][0];     px0.d[1] = pb[2 * wnd][0][1];
      px0.d[2] = pb[2 * wnd + 1][0][0]; px0.d[3] = pb[2 * wnd + 1][0][1];
      px1.d[0] = pb[2 * wnd][1][0];     px1.d[1] = pb[2 * wnd][1][1];
      px1.d[2] = pb[2 * wnd + 1][1][0]; px1.d[3] = pb[2 * wnd + 1][1][1];
      Ls[0] = MFMA(vones, px0.v, Ls[0]);
      Ls[1] = MFMA(vones, px1.v, Ls[1]);
#pragma unroll
      for (int db = 0; db < 4; db++) {
        bfrag vf = *(const bfrag*)(&Vt[buf][((db * 2 + wnd) * 64 + lane) * 8]);
        O[db][0] = MFMA(vf, px0.v, O[db][0]);
        O[db][1] = MFMA(vf, px1.v, O[db][1]);
      }
    }
    __builtin_amdgcn_s_setprio(0);
  }

  const float rl[2] = {1.0f / Ls[0][0], 1.0f / Ls[1][0]};

  // O^T C-layout: lane holds q=l15, d=quad*4+r. Pack 4 d (8B) per store.
  const size_t obase = ((size_t)b * SEQ) * DM + (size_t)h * DK;
#pragma unroll
  for (int db = 0; db < 4; db++)
#pragma unroll
    for (int i = 0; i < 2; i++) {
      int s = qbase + w * 32 + i * 16 + l15;
      union { u16 u[4]; uint2 d; } o;
#pragma unroll
      for (int r = 0; r < 4; r++) o.u[r] = f2bf(O[db][i][r] * rl[i]);
      *(uint2*)(&Ab[obase + (size_t)s * DM + db * 16 + quad * 4]) = o.d;
    }
}

extern "C" void kernel_launch(void* const* d_in, const int* in_sizes, int n_in,
                              void* d_out, int out_size, void* d_ws, size_t ws_size,
                              hipStream_t stream) {
  const float* x  = (const float*)d_in[0];
  const float* Wq = (const float*)d_in[1];
  const float* Wk = (const float*)d_in[2];
  const float* Wv = (const float*)d_in[3];
  const float* Wo = (const float*)d_in[4];
  float* out = (float*)d_out;

  char* ws = (char*)d_ws;
  u16* xb  = (u16*)(ws + 0);          // 16 MB
  u16* Wqb = (u16*)(ws + 16777216);
  u16* Wkb = (u16*)(ws + 18874368);
  u16* Wvb = (u16*)(ws + 20971520);
  u16* Wob = (u16*)(ws + 23068672);
  u16* Qb  = (u16*)(ws + 25165824);   // [B,H,S,DK]
  u16* Ksw = (u16*)(ws + 41943040);   // [B,H] x 32 tiles x swizzled 64x64
  u16* Vsw = (u16*)(ws + 58720256);   // [B,H] x 32 tiles x swizzled 64x64 (x32-PV)
  u16* Ab  = (u16*)(ws + 75497472);   // [B,S,DM]
  const size_t NEED = 92274688;
  if (ws_size < NEED) return;

  cvt_all<<<12288, 256, 0, stream>>>(x, Wq, Wk, Wv, Wo, xb, Wqb, Wkb, Wvb, Wob);

  gemm_qkv<<<1536, 256, 0, stream>>>(xb, Wqb, Wkb, Wvb, Qb, Ksw, Vsw);

  dim3 gat(BATCH * NH, SEQ / 128);
  attn<<<gat, 256, 0, stream>>>(Qb, Ksw, Vsw, Ab);

  gemm_out<<<512, 256, 0, stream>>>(Ab, Wob, out);
}